// Round 16
// baseline (80.580 us; speedup 1.0000x reference)
//
#include <hip/hip_runtime.h>
#include <math.h>

// DCCA loss: H1,H2 (m=2048, n=64, k=128) fp32.
// gram: 3-JOB wave-private split, zero barriers (r11's port-saturated regime) at
//       2.0x traffic (vs r11's 2.5x), 3072 waves (vs r13's starved 2048):
//         j1 = S11 quads (reads H1B0,H1B1)      3 accs
//         j2 = S22 quads (reads H2B0,H2B1)      3 accs
//         j3 = S12 quads (reads all 4 units)    4 accs
//       Each wave stages its k-quarter units into PRIVATE LDS (coalesced loads,
//       bf16 hi/lo, granule-XOR swizzle); block's 3 jobs cover all 10 quads ->
//       non-atomic slab dump, no __syncthreads anywhere.
// reduce: 160x1024 tree-reduce of 1024 slabs (42MB).
// solve: MFMA Newton inverse (2 iters, validated), corr^2 = <X1, S12 X2 S12^T>.
#define TPB 2
#define GRID1 1024             // gram blocks / partial slabs (TPB tiles each)

// c = (1 - 1/m)^2 / (m*(m-1)) = 2047 / 2048^3
#define CSCALE 2.3830240e-7f
#define RIDGE 1e-4f

typedef __bf16 bf16x8 __attribute__((ext_vector_type(8)));
typedef float f32x16 __attribute__((ext_vector_type(16)));

#define MFMA32(A, B, C) __builtin_amdgcn_mfma_f32_32x32x16_bf16(A, B, C, 0, 0, 0)

// global quad id q -> (matrix, row-block, col-block); q0..2 S11, 3..5 S22, 6..9 S12
__device__ __constant__ int kMat[10] = {0,0,0, 1,1,1, 2,2,2,2};
__device__ __constant__ int kQi [10] = {0,1,1, 0,1,1, 0,0,1,1};
__device__ __constant__ int kQj [10] = {0,0,1, 0,0,1, 0,1,0,1};

#define CVT8(a, b, hi, lo) do {                                   \
    float fv[8] = {a.x, a.y, a.z, a.w, b.x, b.y, b.z, b.w};       \
    _Pragma("unroll")                                             \
    for (int j = 0; j < 8; ++j) {                                 \
        __bf16 h = (__bf16)fv[j];                                 \
        hi[j] = h;                                                \
        lo[j] = (__bf16)(fv[j] - (float)h);                       \
    }                                                             \
} while (0)

// Per-wave LDS region layout: units of 2048 bf16 (hi plane [0,1024), lo [1024,2048)),
// unit-quarter = 32 rows x 32 cols, row stride 32 bf16, granule g stored at g^(row&3).
// Regions (bf16): w0 (j1): [0,4096)  w1 (j2): [4096,8192)  w2 (j3): [8192,16384)
template <bool PARTIALS>
__global__ __launch_bounds__(192, 2) void gram_kernel(const float* __restrict__ H1,
                                                      const float* __restrict__ H2,
                                                      float* __restrict__ sig,
                                                      float* __restrict__ part) {
    __shared__ __attribute__((aligned(16))) __bf16 lds[16384];  // 32 KB
    const int tid = threadIdx.x;
    const int w = tid >> 6;       // job id 0/1/2
    const int lane = tid & 63;
    const int l31 = lane & 31;
    const int lhi = lane >> 5;

    __bf16* reg = lds + ((w == 0) ? 0 : (w == 1) ? 4096 : 8192);
    const int nunits = (w < 2) ? 2 : 4;

    f32x16 a0 = {}, a1 = {}, a2 = {}, a3 = {};

    // staging geometry (per unit-quarter): lane covers row l>>1, cols (l&1)*16..+16
    const int srow = lane >> 1;
    const int scol = (lane & 1) * 16;
    const int sg0 = (lane & 1) * 2;              // logical granules sg0, sg0+1
    const int spg0 = (sg0 ^ (srow & 3)) * 8;     // physical byte-granule offsets
    const int spg1 = ((sg0 + 1) ^ (srow & 3)) * 8;

    #pragma unroll 1
    for (int t = 0; t < TPB; ++t) {
        const size_t tb = (size_t)(blockIdx.x * TPB + t) * 8192;
        #pragma unroll
        for (int kq = 0; kq < 4; ++kq) {
            const size_t qb = tb + kq * 32;
            // ---- stage this wave's units (coalesced, wave-private, no sync) ----
            #pragma unroll
            for (int u = 0; u < 4; ++u) {
                if (u < nunits) {
                    // unit -> (view, blk): j1: H1B0,H1B1; j2: H2B0,H2B1; j3: H1B0,H1B1,H2B0,H2B1
                    const float* src;
                    if (w == 0)      src = H1 + qb + (size_t)(u * 32 + srow) * 128 + scol;
                    else if (w == 1) src = H2 + qb + (size_t)(u * 32 + srow) * 128 + scol;
                    else src = ((u < 2) ? H1 : H2) + qb + (size_t)((u & 1) * 32 + srow) * 128 + scol;
                    float4 x0 = *(const float4*)src;
                    float4 y0 = *(const float4*)(src + 4);
                    float4 x1 = *(const float4*)(src + 8);
                    float4 y1 = *(const float4*)(src + 12);
                    bf16x8 h0, l0, h1, l1;
                    CVT8(x0, y0, h0, l0);
                    CVT8(x1, y1, h1, l1);
                    __bf16* ub = reg + u * 2048 + srow * 32;
                    *(bf16x8*)&ub[spg0] = h0;
                    *(bf16x8*)&ub[1024 + spg0] = l0;
                    *(bf16x8*)&ub[spg1] = h1;
                    *(bf16x8*)&ub[1024 + spg1] = l1;
                }
            }
            // ---- consume: 2 k-steps of 16 cols ----
            #pragma unroll
            for (int kt = 0; kt < 2; ++kt) {
                const int gl = kt * 2 + lhi;
                const int pg = (gl ^ (l31 & 3)) * 8;
                const __bf16* r0 = reg + l31 * 32 + pg;
                if (w < 2) {
                    bf16x8 h0 = *(const bf16x8*)&r0[0];
                    bf16x8 l0 = *(const bf16x8*)&r0[1024];
                    bf16x8 h1 = *(const bf16x8*)&r0[2048];
                    bf16x8 l1 = *(const bf16x8*)&r0[3072];
                    a0 = MFMA32(h0, h0, a0); a0 = MFMA32(h0, l0, a0); a0 = MFMA32(l0, h0, a0);
                    a1 = MFMA32(h1, h0, a1); a1 = MFMA32(h1, l0, a1); a1 = MFMA32(l1, h0, a1);
                    a2 = MFMA32(h1, h1, a2); a2 = MFMA32(h1, l1, a2); a2 = MFMA32(l1, h1, a2);
                } else {
                    bf16x8 A0h = *(const bf16x8*)&r0[0];
                    bf16x8 A0l = *(const bf16x8*)&r0[1024];
                    bf16x8 A1h = *(const bf16x8*)&r0[2048];
                    bf16x8 A1l = *(const bf16x8*)&r0[3072];
                    bf16x8 B0h = *(const bf16x8*)&r0[4096];
                    bf16x8 B0l = *(const bf16x8*)&r0[5120];
                    bf16x8 B1h = *(const bf16x8*)&r0[6144];
                    bf16x8 B1l = *(const bf16x8*)&r0[7168];
                    a0 = MFMA32(A0h, B0h, a0); a0 = MFMA32(A0h, B0l, a0); a0 = MFMA32(A0l, B0h, a0);
                    a1 = MFMA32(A0h, B1h, a1); a1 = MFMA32(A0h, B1l, a1); a1 = MFMA32(A0l, B1h, a1);
                    a2 = MFMA32(A1h, B0h, a2); a2 = MFMA32(A1h, B0l, a2); a2 = MFMA32(A1l, B0h, a2);
                    a3 = MFMA32(A1h, B1h, a3); a3 = MFMA32(A1h, B1l, a3); a3 = MFMA32(A1l, B1h, a3);
                }
            }
        }
    }

    // Dump: the 3 jobs cover all 10 quads disjointly -> non-atomic, no sync.
    // C/D 32x32 layout: col = lane&31, row = (rg&3)+8*(rg>>2)+4*(lane>>5)
    const int q0 = (w == 0) ? 0 : (w == 1) ? 3 : 6;
    const int nq = (w < 2) ? 3 : 4;
    f32x16 A[4] = {a0, a1, a2, a3};
    if (PARTIALS) {
        float* dst = part + (size_t)blockIdx.x * 10240 + q0 * 1024;
        #pragma unroll
        for (int qq = 0; qq < 4; ++qq) {
            if (qq < nq) {
                #pragma unroll
                for (int rg = 0; rg < 16; ++rg) {
                    int row = (rg & 3) + 8 * (rg >> 2) + 4 * lhi;
                    dst[qq * 1024 + row * 32 + l31] = A[qq][rg];
                }
            }
        }
    } else {
        #pragma unroll
        for (int qq = 0; qq < 4; ++qq) {
            if (qq < nq) {
                const int q = q0 + qq;
                #pragma unroll
                for (int rg = 0; rg < 16; ++rg) {
                    int row = (rg & 3) + 8 * (rg >> 2) + 4 * lhi;
                    atomicAdd(&sig[kMat[q] * 4096 + (kQi[q] * 32 + row) * 64 + kQj[q] * 32 + l31],
                              A[qq][rg]);
                }
            }
        }
    }
}

// 160 blocks x 1024 threads: block owns 64 partial-space slots; wave w of 16 sums
// slabs {w, w+16, ...}; cross-wave combine in LDS; scatter into sig.
__global__ __launch_bounds__(1024) void reduce_kernel(const float* __restrict__ part,
                                                      float* __restrict__ sig) {
    __shared__ float buf[16][64];
    const int tid = threadIdx.x;
    const int w = tid >> 6;
    const int lane = tid & 63;
    const int o0 = blockIdx.x * 64;

    float s = 0.0f;
    for (int p = w; p < GRID1; p += 16)
        s += part[(size_t)p * 10240 + o0 + lane];
    buf[w][lane] = s;
    __syncthreads();

    if (w == 0) {
        float v = 0.0f;
        #pragma unroll
        for (int i = 0; i < 16; ++i) v += buf[i][lane];
        int o = o0 + lane;
        int q = o >> 10, idx = o & 1023;
        int r = idx >> 5, c = idx & 31;
        sig[kMat[q] * 4096 + (kQi[q] * 32 + r) * 64 + kQj[q] * 32 + c] = v;
    }
}

// One block, 512 threads (8 waves). Newton inverse on MFMA:
//   X0 = (64/tr A) I;  X <- 2X - X*A*X  (2 iters; validated r13-r15)
//   corr^2 = <X1, S12*X2*S12^T>  transpose-free via mfma(A,B)=A*B^T + symmetry.
#define SST 72
#define SPL (64 * SST)
// plane ids: 0/1 A1 h/l, 2/3 A2 h/l, 4/5 X1 h/l, 6/7 X2 h/l, 8/9 W1|S12 h/l, 10/11 W2|Z h/l

__global__ __launch_bounds__(512, 1) void solve_kernel(const float* __restrict__ sig,
                                                       float* __restrict__ out) {
    __shared__ __attribute__((aligned(16))) __bf16 pl[12 * SPL];
    __shared__ float ainv[2];
    __shared__ float rbuf[4];
    const int tid = threadIdx.x;
    const int w = tid >> 6, lane = tid & 63, l31 = lane & 31, lhi = lane >> 5;
    const int g = w >> 2;          // matrix group: 0 -> S11, 1 -> S22
    const int qw = w & 3, qi = qw >> 1, qj = qw & 1;
    const int ra = qi * 32 + l31;  // A-operand fragment row
    const int rb = qj * 32 + l31;  // B-operand fragment row

    // Load A = CSCALE*Gram + ridge, symmetric reconstruct (sig quad (0,1) is zeros).
    for (int idx = tid; idx < 4096; idx += 512) {
        int r = idx >> 6, c = idx & 63;
        int src = (r < 32 && c >= 32) ? (c * 64 + r) : idx;
        float rg = (r == c) ? RIDGE : 0.0f;
        float v1 = CSCALE * sig[src] + rg;
        float v2 = CSCALE * sig[4096 + src] + rg;
        __bf16 h1 = (__bf16)v1, h2 = (__bf16)v2;
        pl[0 * SPL + r * SST + c] = h1;
        pl[1 * SPL + r * SST + c] = (__bf16)(v1 - (float)h1);
        pl[2 * SPL + r * SST + c] = h2;
        pl[3 * SPL + r * SST + c] = (__bf16)(v2 - (float)h2);
    }
    if (w == 0 || w == 4) {        // alpha_inv = 64 / tr(A)
        int mg = (w == 4);
        float d = CSCALE * sig[mg * 4096 + lane * 65] + RIDGE;
        #pragma unroll
        for (int off = 32; off; off >>= 1) d += __shfl_xor(d, off, 64);
        if (lane == 0) ainv[mg] = 64.0f / d;
    }
    __syncthreads();

    // X0 = ainv * I
    for (int idx = tid; idx < 4096; idx += 512) {
        int r = idx >> 6, c = idx & 63;
        float v1 = (r == c) ? ainv[0] : 0.0f;
        float v2 = (r == c) ? ainv[1] : 0.0f;
        __bf16 h1 = (__bf16)v1, h2 = (__bf16)v2;
        pl[4 * SPL + r * SST + c] = h1;
        pl[5 * SPL + r * SST + c] = (__bf16)(v1 - (float)h1);
        pl[6 * SPL + r * SST + c] = h2;
        pl[7 * SPL + r * SST + c] = (__bf16)(v2 - (float)h2);
    }
    __syncthreads();

    for (int it = 0; it < 2; ++it) {
        // W = X * A
        f32x16 accw = {};
        #pragma unroll
        for (int ks = 0; ks < 4; ++ks) {
            int col = ks * 16 + lhi * 8;
            bf16x8 xh = *(const bf16x8*)&pl[(4 + 2 * g) * SPL + ra * SST + col];
            bf16x8 xl = *(const bf16x8*)&pl[(5 + 2 * g) * SPL + ra * SST + col];
            bf16x8 ah = *(const bf16x8*)&pl[(0 + 2 * g) * SPL + rb * SST + col];
            bf16x8 al = *(const bf16x8*)&pl[(1 + 2 * g) * SPL + rb * SST + col];
            accw = MFMA32(xh, ah, accw);
            accw = MFMA32(xh, al, accw);
            accw = MFMA32(xl, ah, accw);
        }
        #pragma unroll
        for (int rg = 0; rg < 16; ++rg) {
            int row = qi * 32 + (rg & 3) + 8 * (rg >> 2) + 4 * lhi;
            int col = qj * 32 + l31;
            float v = accw[rg];
            __bf16 h = (__bf16)v;
            pl[(8 + 2 * g) * SPL + row * SST + col] = h;
            pl[(9 + 2 * g) * SPL + row * SST + col] = (__bf16)(v - (float)h);
        }
        __syncthreads();

        // S = W * X ; X <- 2X - S
        f32x16 accs = {};
        #pragma unroll
        for (int ks = 0; ks < 4; ++ks) {
            int col = ks * 16 + lhi * 8;
            bf16x8 wh = *(const bf16x8*)&pl[(8 + 2 * g) * SPL + ra * SST + col];
            bf16x8 wl = *(const bf16x8*)&pl[(9 + 2 * g) * SPL + ra * SST + col];
            bf16x8 xh = *(const bf16x8*)&pl[(4 + 2 * g) * SPL + rb * SST + col];
            bf16x8 xl = *(const bf16x8*)&pl[(5 + 2 * g) * SPL + rb * SST + col];
            accs = MFMA32(wh, xh, accs);
            accs = MFMA32(wh, xl, accs);
            accs = MFMA32(wl, xh, accs);
        }
        __syncthreads();   // all X reads done before X writes
        #pragma unroll
        for (int rg = 0; rg < 16; ++rg) {
            int row = qi * 32 + (rg & 3) + 8 * (rg >> 2) + 4 * lhi;
            int col = qj * 32 + l31;
            float xv = (float)pl[(4 + 2 * g) * SPL + row * SST + col]
                     + (float)pl[(5 + 2 * g) * SPL + row * SST + col];
            float nv = 2.0f * xv - accs[rg];
            __bf16 h = (__bf16)nv;
            pl[(4 + 2 * g) * SPL + row * SST + col] = h;
            pl[(5 + 2 * g) * SPL + row * SST + col] = (__bf16)(nv - (float)h);
        }
        __syncthreads();
    }

    // S12 -> planes 8/9
    for (int idx = tid; idx < 4096; idx += 512) {
        int r = idx >> 6, c = idx & 63;
        float v = CSCALE * sig[8192 + idx];
        __bf16 h = (__bf16)v;
        pl[8 * SPL + r * SST + c] = h;
        pl[9 * SPL + r * SST + c] = (__bf16)(v - (float)h);
    }
    __syncthreads();

    // Z = S12 * X2 -> planes 10/11 (group 1)
    if (g == 1) {
        f32x16 accz = {};
        #pragma unroll
        for (int ks = 0; ks < 4; ++ks) {
            int col = ks * 16 + lhi * 8;
            bf16x8 sh = *(const bf16x8*)&pl[8 * SPL + ra * SST + col];
            bf16x8 sl = *(const bf16x8*)&pl[9 * SPL + ra * SST + col];
            bf16x8 xh = *(const bf16x8*)&pl[6 * SPL + rb * SST + col];
            bf16x8 xl = *(const bf16x8*)&pl[7 * SPL + rb * SST + col];
            accz = MFMA32(sh, xh, accz);
            accz = MFMA32(sh, xl, accz);
            accz = MFMA32(sl, xh, accz);
        }
        #pragma unroll
        for (int rg = 0; rg < 16; ++rg) {
            int row = qi * 32 + (rg & 3) + 8 * (rg >> 2) + 4 * lhi;
            int col = qj * 32 + l31;
            float v = accz[rg];
            __bf16 h = (__bf16)v;
            pl[10 * SPL + row * SST + col] = h;
            pl[11 * SPL + row * SST + col] = (__bf16)(v - (float)h);
        }
    }
    __syncthreads();

    // M = Z * S12^T (group 0); corr^2 += M .* X1
    if (g == 0) {
        f32x16 accm = {};
        #pragma unroll
        for (int ks = 0; ks < 4; ++ks) {
            int col = ks * 16 + lhi * 8;
            bf16x8 zh = *(const bf16x8*)&pl[10 * SPL + ra * SST + col];
            bf16x8 zl = *(const bf16x8*)&pl[11 * SPL + ra * SST + col];
            bf16x8 sh = *(const bf16x8*)&pl[8 * SPL + rb * SST + col];
            bf16x8 sl = *(const bf16x8*)&pl[9 * SPL + rb * SST + col];
            accm = MFMA32(zh, sh, accm);
            accm = MFMA32(zh, sl, accm);
            accm = MFMA32(zl, sh, accm);
        }
        float p = 0.0f;
        #pragma unroll
        for (int rg = 0; rg < 16; ++rg) {
            int row = qi * 32 + (rg & 3) + 8 * (rg >> 2) + 4 * lhi;
            int col = qj * 32 + l31;
            float x1v = (float)pl[4 * SPL + row * SST + col]
                      + (float)pl[5 * SPL + row * SST + col];
            p += accm[rg] * x1v;
        }
        #pragma unroll
        for (int off = 32; off; off >>= 1) p += __shfl_xor(p, off, 64);
        if (lane == 0) rbuf[qw] = p;
    }
    __syncthreads();
    if (tid == 0) out[0] = -sqrtf(rbuf[0] + rbuf[1] + rbuf[2] + rbuf[3]);
}

extern "C" void kernel_launch(void* const* d_in, const int* in_sizes, int n_in,
                              void* d_out, int out_size, void* d_ws, size_t ws_size,
                              hipStream_t stream) {
    const float* H1 = (const float*)d_in[0];
    const float* H2 = (const float*)d_in[1];
    float* sig = (float*)d_ws;                      // 12288 floats = 48 KB
    float* part = (float*)((char*)d_ws + 49152);    // 1024 * 10240 floats = 40 MB
    const size_t need = 49152 + (size_t)GRID1 * 10240 * 4;

    if (ws_size >= need) {
        // No memset needed: reduce_kernel overwrites every sig slot solve reads.
        gram_kernel<true><<<GRID1, 192, 0, stream>>>(H1, H2, sig, part);
        reduce_kernel<<<160, 1024, 0, stream>>>(part, sig);
    } else {
        hipMemsetAsync(d_ws, 0, 49152, stream);
        gram_kernel<false><<<GRID1, 192, 0, stream>>>(H1, H2, sig, nullptr);
    }
    solve_kernel<<<1, 512, 0, stream>>>(sig, (float*)d_out);
}

// Round 17
// 54.389 us; speedup vs baseline: 1.4816x; 1.4816x over previous
//
#include <hip/hip_runtime.h>
#include <math.h>

// DCCA loss: H1,H2 (m=2048, n=64, k=128) fp32.
// FINAL CONFIG (best measured, r15 = 54.2us total, absmax 0.0):
// gram: TPB=4, full-K LDS staging (69.6KB, RSU=136, 0 conflicts), 4 job-split
//       waves, non-atomic slab dump. 50.2-52us measured across r4/r5/r15.
// reduce: 160x1024 tree-reduce of 512 slabs (20MB), ~2us.
// solve: MFMA Newton inverse, 2 iters (validated r13-r15), corr^2 = <X1,S12 X2 S12^T>.
//
// Plateau evidence (r6-r16): cooperative 1x-traffic structures are barrier/vmcnt-
// drain bound at ~50us (HIP compiler drains all outstanding loads at every
// __syncthreads); barrier-free wave-private structures saturate the vector port
// (6.2 TB/s measured, r11) but pay >=1.75x traffic amplification. Both branches
// floor at ~50us for this problem shape.
#define TPB 4
#define GRID1 512              // gram blocks / partial slabs
#define RSU 136                // LDS row stride in bf16 (272B; 0 conflicts measured)
#define PLANE (64 * RSU)

// c = (1 - 1/m)^2 / (m*(m-1)) = 2047 / 2048^3
#define CSCALE 2.3830240e-7f
#define RIDGE 1e-4f

typedef __bf16 bf16x8 __attribute__((ext_vector_type(8)));
typedef float f32x16 __attribute__((ext_vector_type(16)));

#define MFMA32(A, B, C) __builtin_amdgcn_mfma_f32_32x32x16_bf16(A, B, C, 0, 0, 0)

// global quad id q -> (matrix, row-block, col-block); q0..2 S11, 3..5 S22, 6..9 S12
__device__ __constant__ int kMat[10] = {0,0,0, 1,1,1, 2,2,2,2};
__device__ __constant__ int kQi [10] = {0,1,1, 0,1,1, 0,0,1,1};
__device__ __constant__ int kQj [10] = {0,0,1, 0,0,1, 0,1,0,1};

template <bool PARTIALS>
__global__ __launch_bounds__(256, 2) void gram_kernel(const float* __restrict__ H1,
                                                      const float* __restrict__ H2,
                                                      float* __restrict__ sig,
                                                      float* __restrict__ part) {
    __shared__ __bf16 lds[4 * PLANE];   // planes: 0=H1hi 1=H1lo 2=H2hi 3=H2lo (69632 B)
    const int tid = threadIdx.x;
    const int w = tid >> 6;
    const int lane = tid & 63;
    const int l31 = lane & 31;
    const int lhi = lane >> 5;

    // wave job: w0 -> S11 quads (0,0),(1,0),(1,1); w1 -> S22 same;
    //           w2 -> S12 rows 0-31; w3 -> S12 rows 32-63
    f32x16 a0 = {}, a1 = {}, a2 = {};

    for (int t = 0; t < TPB; ++t) {
        const size_t base = (size_t)(blockIdx.x * TPB + t) * (64 * 128);
        __syncthreads();  // protect LDS vs previous tile's readers
        #pragma unroll
        for (int v = 0; v < 2; ++v) {
            const float* __restrict__ Hsrc = (v ? H2 : H1) + base;
            __bf16* ph = lds + 2 * v * PLANE;
            __bf16* pllo = ph + PLANE;
            #pragma unroll
            for (int it = 0; it < 4; ++it) {
                int chunk = it * 256 + tid;          // 1024 chunks of 8 floats
                int r = chunk >> 4, c8 = chunk & 15;
                const float* src = Hsrc + r * 128 + c8 * 8;
                float4 u0 = *(const float4*)src;
                float4 u1 = *(const float4*)(src + 4);
                float fv[8] = {u0.x, u0.y, u0.z, u0.w, u1.x, u1.y, u1.z, u1.w};
                bf16x8 hi, lo;
                #pragma unroll
                for (int j = 0; j < 8; ++j) {
                    __bf16 h = (__bf16)fv[j];
                    hi[j] = h;
                    lo[j] = (__bf16)(fv[j] - (float)h);
                }
                *(bf16x8*)&ph[r * RSU + c8 * 8] = hi;
                *(bf16x8*)&pllo[r * RSU + c8 * 8] = lo;
            }
        }
        __syncthreads();

        if (w < 2) {
            const __bf16* ph = lds + 2 * w * PLANE;
            const __bf16* pllo = ph + PLANE;
            #pragma unroll
            for (int kt = 0; kt < 8; ++kt) {
                const int col = kt * 16 + lhi * 8;
                bf16x8 h0 = *(const bf16x8*)&ph[l31 * RSU + col];
                bf16x8 h1 = *(const bf16x8*)&ph[(32 + l31) * RSU + col];
                bf16x8 l0 = *(const bf16x8*)&pllo[l31 * RSU + col];
                bf16x8 l1 = *(const bf16x8*)&pllo[(32 + l31) * RSU + col];
                a0 = MFMA32(h0, h0, a0); a0 = MFMA32(h0, l0, a0); a0 = MFMA32(l0, h0, a0);
                a1 = MFMA32(h1, h0, a1); a1 = MFMA32(h1, l0, a1); a1 = MFMA32(l1, h0, a1);
                a2 = MFMA32(h1, h1, a2); a2 = MFMA32(h1, l1, a2); a2 = MFMA32(l1, h1, a2);
            }
        } else {
            const int arow = ((w == 3) ? 32 : 0) + l31;
            #pragma unroll
            for (int kt = 0; kt < 8; ++kt) {
                const int col = kt * 16 + lhi * 8;
                bf16x8 Ahf = *(const bf16x8*)&lds[0 * PLANE + arow * RSU + col];
                bf16x8 Alf = *(const bf16x8*)&lds[1 * PLANE + arow * RSU + col];
                bf16x8 B0h = *(const bf16x8*)&lds[2 * PLANE + l31 * RSU + col];
                bf16x8 B0l = *(const bf16x8*)&lds[3 * PLANE + l31 * RSU + col];
                bf16x8 B1h = *(const bf16x8*)&lds[2 * PLANE + (32 + l31) * RSU + col];
                bf16x8 B1l = *(const bf16x8*)&lds[3 * PLANE + (32 + l31) * RSU + col];
                a0 = MFMA32(Ahf, B0h, a0); a0 = MFMA32(Ahf, B0l, a0); a0 = MFMA32(Alf, B0h, a0);
                a1 = MFMA32(Ahf, B1h, a1); a1 = MFMA32(Ahf, B1l, a1); a1 = MFMA32(Alf, B1h, a1);
            }
        }
    }

    // Flush: quads are wave-disjoint -> non-atomic partial dump (or atomic fallback).
    const int q0 = (w == 0) ? 0 : (w == 1) ? 3 : (w == 2) ? 6 : 8;
    const int nq = (w < 2) ? 3 : 2;
    f32x16 A[3] = {a0, a1, a2};
    if (PARTIALS) {
        float* dst = part + (size_t)blockIdx.x * 10240 + q0 * 1024;
        #pragma unroll
        for (int qq = 0; qq < 3; ++qq) {
            if (qq < nq) {
                #pragma unroll
                for (int rg = 0; rg < 16; ++rg) {
                    // C/D 32x32 layout: col = lane&31, row = (rg&3)+8*(rg>>2)+4*(lane>>5)
                    int row = (rg & 3) + 8 * (rg >> 2) + 4 * lhi;
                    dst[qq * 1024 + row * 32 + l31] = A[qq][rg];
                }
            }
        }
    } else {
        #pragma unroll
        for (int qq = 0; qq < 3; ++qq) {
            if (qq < nq) {
                const int q = q0 + qq;
                #pragma unroll
                for (int rg = 0; rg < 16; ++rg) {
                    int row = (rg & 3) + 8 * (rg >> 2) + 4 * lhi;
                    atomicAdd(&sig[kMat[q] * 4096 + (kQi[q] * 32 + row) * 64 + kQj[q] * 32 + l31],
                              A[qq][rg]);
                }
            }
        }
    }
}

// 160 blocks x 1024 threads: block owns 64 partial-space slots; wave w of 16 sums
// slabs {w, w+16, ...} (32-deep chains); cross-wave combine in LDS; scatter into sig.
__global__ __launch_bounds__(1024) void reduce_kernel(const float* __restrict__ part,
                                                      float* __restrict__ sig) {
    __shared__ float buf[16][64];
    const int tid = threadIdx.x;
    const int w = tid >> 6;
    const int lane = tid & 63;
    const int o0 = blockIdx.x * 64;

    float s = 0.0f;
    for (int p = w; p < GRID1; p += 16)
        s += part[(size_t)p * 10240 + o0 + lane];
    buf[w][lane] = s;
    __syncthreads();

    if (w == 0) {
        float v = 0.0f;
        #pragma unroll
        for (int i = 0; i < 16; ++i) v += buf[i][lane];
        int o = o0 + lane;
        int q = o >> 10, idx = o & 1023;
        int r = idx >> 5, c = idx & 31;
        sig[kMat[q] * 4096 + (kQi[q] * 32 + r) * 64 + kQj[q] * 32 + c] = v;
    }
}

// One block, 512 threads (8 waves). Newton inverse on MFMA:
//   X0 = (64/tr A) I;  X <- 2X - X*A*X  (2 iters; residual ~2.6e-6, validated)
//   corr^2 = <X1, S12*X2*S12^T>  transpose-free via mfma(A,B)=A*B^T + symmetry.
#define SST 72
#define SPL (64 * SST)
// plane ids: 0/1 A1 h/l, 2/3 A2 h/l, 4/5 X1 h/l, 6/7 X2 h/l, 8/9 W1|S12 h/l, 10/11 W2|Z h/l

__global__ __launch_bounds__(512, 1) void solve_kernel(const float* __restrict__ sig,
                                                       float* __restrict__ out) {
    __shared__ __attribute__((aligned(16))) __bf16 pl[12 * SPL];
    __shared__ float ainv[2];
    __shared__ float rbuf[4];
    const int tid = threadIdx.x;
    const int w = tid >> 6, lane = tid & 63, l31 = lane & 31, lhi = lane >> 5;
    const int g = w >> 2;          // matrix group: 0 -> S11, 1 -> S22
    const int qw = w & 3, qi = qw >> 1, qj = qw & 1;
    const int ra = qi * 32 + l31;  // A-operand fragment row
    const int rb = qj * 32 + l31;  // B-operand fragment row

    // Load A = CSCALE*Gram + ridge, symmetric reconstruct (sig quad (0,1) is zeros).
    for (int idx = tid; idx < 4096; idx += 512) {
        int r = idx >> 6, c = idx & 63;
        int src = (r < 32 && c >= 32) ? (c * 64 + r) : idx;
        float rg = (r == c) ? RIDGE : 0.0f;
        float v1 = CSCALE * sig[src] + rg;
        float v2 = CSCALE * sig[4096 + src] + rg;
        __bf16 h1 = (__bf16)v1, h2 = (__bf16)v2;
        pl[0 * SPL + r * SST + c] = h1;
        pl[1 * SPL + r * SST + c] = (__bf16)(v1 - (float)h1);
        pl[2 * SPL + r * SST + c] = h2;
        pl[3 * SPL + r * SST + c] = (__bf16)(v2 - (float)h2);
    }
    if (w == 0 || w == 4) {        // alpha_inv = 64 / tr(A)
        int mg = (w == 4);
        float d = CSCALE * sig[mg * 4096 + lane * 65] + RIDGE;
        #pragma unroll
        for (int off = 32; off; off >>= 1) d += __shfl_xor(d, off, 64);
        if (lane == 0) ainv[mg] = 64.0f / d;
    }
    __syncthreads();

    // X0 = ainv * I
    for (int idx = tid; idx < 4096; idx += 512) {
        int r = idx >> 6, c = idx & 63;
        float v1 = (r == c) ? ainv[0] : 0.0f;
        float v2 = (r == c) ? ainv[1] : 0.0f;
        __bf16 h1 = (__bf16)v1, h2 = (__bf16)v2;
        pl[4 * SPL + r * SST + c] = h1;
        pl[5 * SPL + r * SST + c] = (__bf16)(v1 - (float)h1);
        pl[6 * SPL + r * SST + c] = h2;
        pl[7 * SPL + r * SST + c] = (__bf16)(v2 - (float)h2);
    }
    __syncthreads();

    for (int it = 0; it < 2; ++it) {
        // W = X * A
        f32x16 accw = {};
        #pragma unroll
        for (int ks = 0; ks < 4; ++ks) {
            int col = ks * 16 + lhi * 8;
            bf16x8 xh = *(const bf16x8*)&pl[(4 + 2 * g) * SPL + ra * SST + col];
            bf16x8 xl = *(const bf16x8*)&pl[(5 + 2 * g) * SPL + ra * SST + col];
            bf16x8 ah = *(const bf16x8*)&pl[(0 + 2 * g) * SPL + rb * SST + col];
            bf16x8 al = *(const bf16x8*)&pl[(1 + 2 * g) * SPL + rb * SST + col];
            accw = MFMA32(xh, ah, accw);
            accw = MFMA32(xh, al, accw);
            accw = MFMA32(xl, ah, accw);
        }
        #pragma unroll
        for (int rg = 0; rg < 16; ++rg) {
            int row = qi * 32 + (rg & 3) + 8 * (rg >> 2) + 4 * lhi;
            int col = qj * 32 + l31;
            float v = accw[rg];
            __bf16 h = (__bf16)v;
            pl[(8 + 2 * g) * SPL + row * SST + col] = h;
            pl[(9 + 2 * g) * SPL + row * SST + col] = (__bf16)(v - (float)h);
        }
        __syncthreads();

        // S = W * X ; X <- 2X - S
        f32x16 accs = {};
        #pragma unroll
        for (int ks = 0; ks < 4; ++ks) {
            int col = ks * 16 + lhi * 8;
            bf16x8 wh = *(const bf16x8*)&pl[(8 + 2 * g) * SPL + ra * SST + col];
            bf16x8 wl = *(const bf16x8*)&pl[(9 + 2 * g) * SPL + ra * SST + col];
            bf16x8 xh = *(const bf16x8*)&pl[(4 + 2 * g) * SPL + rb * SST + col];
            bf16x8 xl = *(const bf16x8*)&pl[(5 + 2 * g) * SPL + rb * SST + col];
            accs = MFMA32(wh, xh, accs);
            accs = MFMA32(wh, xl, accs);
            accs = MFMA32(wl, xh, accs);
        }
        __syncthreads();   // all X reads done before X writes
        #pragma unroll
        for (int rg = 0; rg < 16; ++rg) {
            int row = qi * 32 + (rg & 3) + 8 * (rg >> 2) + 4 * lhi;
            int col = qj * 32 + l31;
            float xv = (float)pl[(4 + 2 * g) * SPL + row * SST + col]
                     + (float)pl[(5 + 2 * g) * SPL + row * SST + col];
            float nv = 2.0f * xv - accs[rg];
            __bf16 h = (__bf16)nv;
            pl[(4 + 2 * g) * SPL + row * SST + col] = h;
            pl[(5 + 2 * g) * SPL + row * SST + col] = (__bf16)(nv - (float)h);
        }
        __syncthreads();
    }

    // S12 -> planes 8/9
    for (int idx = tid; idx < 4096; idx += 512) {
        int r = idx >> 6, c = idx & 63;
        float v = CSCALE * sig[8192 + idx];
        __bf16 h = (__bf16)v;
        pl[8 * SPL + r * SST + c] = h;
        pl[9 * SPL + r * SST + c] = (__bf16)(v - (float)h);
    }
    __syncthreads();

    // Z = S12 * X2 -> planes 10/11 (group 1)
    if (g == 1) {
        f32x16 accz = {};
        #pragma unroll
        for (int ks = 0; ks < 4; ++ks) {
            int col = ks * 16 + lhi * 8;
            bf16x8 sh = *(const bf16x8*)&pl[8 * SPL + ra * SST + col];
            bf16x8 sl = *(const bf16x8*)&pl[9 * SPL + ra * SST + col];
            bf16x8 xh = *(const bf16x8*)&pl[6 * SPL + rb * SST + col];
            bf16x8 xl = *(const bf16x8*)&pl[7 * SPL + rb * SST + col];
            accz = MFMA32(sh, xh, accz);
            accz = MFMA32(sh, xl, accz);
            accz = MFMA32(sl, xh, accz);
        }
        #pragma unroll
        for (int rg = 0; rg < 16; ++rg) {
            int row = qi * 32 + (rg & 3) + 8 * (rg >> 2) + 4 * lhi;
            int col = qj * 32 + l31;
            float v = accz[rg];
            __bf16 h = (__bf16)v;
            pl[10 * SPL + row * SST + col] = h;
            pl[11 * SPL + row * SST + col] = (__bf16)(v - (float)h);
        }
    }
    __syncthreads();

    // M = Z * S12^T (group 0); corr^2 += M .* X1
    if (g == 0) {
        f32x16 accm = {};
        #pragma unroll
        for (int ks = 0; ks < 4; ++ks) {
            int col = ks * 16 + lhi * 8;
            bf16x8 zh = *(const bf16x8*)&pl[10 * SPL + ra * SST + col];
            bf16x8 zl = *(const bf16x8*)&pl[11 * SPL + ra * SST + col];
            bf16x8 sh = *(const bf16x8*)&pl[8 * SPL + rb * SST + col];
            bf16x8 sl = *(const bf16x8*)&pl[9 * SPL + rb * SST + col];
            accm = MFMA32(zh, sh, accm);
            accm = MFMA32(zh, sl, accm);
            accm = MFMA32(zl, sh, accm);
        }
        float p = 0.0f;
        #pragma unroll
        for (int rg = 0; rg < 16; ++rg) {
            int row = qi * 32 + (rg & 3) + 8 * (rg >> 2) + 4 * lhi;
            int col = qj * 32 + l31;
            float x1v = (float)pl[4 * SPL + row * SST + col]
                      + (float)pl[5 * SPL + row * SST + col];
            p += accm[rg] * x1v;
        }
        #pragma unroll
        for (int off = 32; off; off >>= 1) p += __shfl_xor(p, off, 64);
        if (lane == 0) rbuf[qw] = p;
    }
    __syncthreads();
    if (tid == 0) out[0] = -sqrtf(rbuf[0] + rbuf[1] + rbuf[2] + rbuf[3]);
}

extern "C" void kernel_launch(void* const* d_in, const int* in_sizes, int n_in,
                              void* d_out, int out_size, void* d_ws, size_t ws_size,
                              hipStream_t stream) {
    const float* H1 = (const float*)d_in[0];
    const float* H2 = (const float*)d_in[1];
    float* sig = (float*)d_ws;                      // 12288 floats = 48 KB
    float* part = (float*)((char*)d_ws + 49152);    // 512 * 10240 floats = 20 MB
    const size_t need = 49152 + (size_t)GRID1 * 10240 * 4;

    if (ws_size >= need) {
        // No memset needed: reduce_kernel overwrites every sig slot solve reads.
        gram_kernel<true><<<GRID1, 256, 0, stream>>>(H1, H2, sig, part);
        reduce_kernel<<<160, 1024, 0, stream>>>(part, sig);
    } else {
        hipMemsetAsync(d_ws, 0, 49152, stream);
        gram_kernel<false><<<GRID1, 256, 0, stream>>>(H1, H2, sig, nullptr);
    }
    solve_kernel<<<1, 512, 0, stream>>>(sig, (float*)d_out);
}